// Round 16
// baseline (400.557 us; speedup 1.0000x reference)
//
#include <hip/hip_runtime.h>
#include <stdint.h>

// NCA: B=8, C=16, H=W=128, hidden=128, 8 steps.
// step_a rewritten on MFMA (bf16 3-term split = fp32-level accuracy).
// Everything else (fmaskzero in-place zeroing, mask riding, step_b) = r12/r15.
// ws: [0,8MB) midA, [8MB,16MB) midB, [+512KB) mid3c, [+128KB) pre,
//     [+2MB) mask, [+16KB) w1h, [+16KB) w1l, [+4KB) w2h, [+4KB) w2l. ~19MB.

#define BATCH 8
#define CH 16
#define HT 128
#define WD 128
#define HIDN 128
#define PLANE (HT*WD)
#define IMG (CH*PLANE)
#define NELEM (BATCH*IMG)
#define NPIX (BATCH*PLANE)
#define WORDS_PER_STEP (NELEM/32)   // 65536
#define NSTEPS 8
#define NPIXB 64
#define NGRP (NPIX/NPIXB)           // 2048

typedef __attribute__((ext_vector_type(8))) short short8;   // 8 bf16 (4 VGPR)
typedef __attribute__((ext_vector_type(4))) float f32x4;

__device__ __forceinline__ short bf16_rne(float v) {
  unsigned u = __float_as_uint(v);
  return (short)((u + 0x7fffu + ((u >> 16) & 1u)) >> 16);
}
__device__ __forceinline__ float bf16_to_f(short s) {
  return __uint_as_float(((unsigned)(unsigned short)s) << 16);
}

__host__ __device__ __forceinline__ unsigned rotl32u(unsigned v, int r) {
  return (v << r) | (v >> (32 - r));
}

// JAX threefry2x32 (20 rounds).
__host__ __device__ __forceinline__ void tf2x32(unsigned k0, unsigned k1,
                                                unsigned c0, unsigned c1,
                                                unsigned &o0, unsigned &o1) {
  const unsigned ks2 = k0 ^ k1 ^ 0x1BD11BDAu;
  unsigned x0 = c0 + k0, x1 = c1 + k1;
  x0 += x1; x1 = rotl32u(x1, 13); x1 ^= x0;
  x0 += x1; x1 = rotl32u(x1, 15); x1 ^= x0;
  x0 += x1; x1 = rotl32u(x1, 26); x1 ^= x0;
  x0 += x1; x1 = rotl32u(x1,  6); x1 ^= x0;
  x0 += k1; x1 += ks2 + 1u;
  x0 += x1; x1 = rotl32u(x1, 17); x1 ^= x0;
  x0 += x1; x1 = rotl32u(x1, 29); x1 ^= x0;
  x0 += x1; x1 = rotl32u(x1, 16); x1 ^= x0;
  x0 += x1; x1 = rotl32u(x1, 24); x1 ^= x0;
  x0 += ks2; x1 += k0 + 2u;
  x0 += x1; x1 = rotl32u(x1, 13); x1 ^= x0;
  x0 += x1; x1 = rotl32u(x1, 15); x1 ^= x0;
  x0 += x1; x1 = rotl32u(x1, 26); x1 ^= x0;
  x0 += x1; x1 = rotl32u(x1,  6); x1 ^= x0;
  x0 += k0; x1 += k1 + 3u;
  x0 += x1; x1 = rotl32u(x1, 17); x1 ^= x0;
  x0 += x1; x1 = rotl32u(x1, 29); x1 ^= x0;
  x0 += x1; x1 = rotl32u(x1, 16); x1 ^= x0;
  x0 += x1; x1 = rotl32u(x1, 24); x1 ^= x0;
  x0 += k1; x1 += ks2 + 4u;
  x0 += x1; x1 = rotl32u(x1, 13); x1 ^= x0;
  x0 += x1; x1 = rotl32u(x1, 15); x1 ^= x0;
  x0 += x1; x1 = rotl32u(x1, 26); x1 ^= x0;
  x0 += x1; x1 = rotl32u(x1,  6); x1 ^= x0;
  x0 += ks2; x1 += k0 + 5u;
  o0 = x0; o1 = x1;
}

__device__ __forceinline__ void mask_word_body(unsigned* __restrict__ mask,
                                               unsigned k0, unsigned k1,
                                               unsigned w) {
  unsigned base = w << 5;
  unsigned word = 0u;
  #pragma unroll 4
  for (int i = 0; i < 32; ++i) {
    unsigned b1x, b2x;
    tf2x32(k0, k1, 0u, base + (unsigned)i, b1x, b2x);
    word |= ((((b1x ^ b2x) >> 9) != 0u) ? 1u : 0u) << i;
  }
  mask[w] = word;
}

// Prologue: step-0 mask + bf16 hi/lo weight split.
// w1h/w1l[h][64] (k padded 48..63 = 0); w2h/w2l[o][128]. No transposes —
// the MFMA B-operand layout (n=lane&15, k=quad*8+j) matches row-major.
__global__ __launch_bounds__(256) void wpack_mask0_kernel(
    const float* __restrict__ w1, const float* __restrict__ w2,
    short* __restrict__ w1h, short* __restrict__ w1l,
    short* __restrict__ w2h, short* __restrict__ w2l,
    unsigned* __restrict__ mask, unsigned k0, unsigned k1) {
  unsigned t = blockIdx.x * 256u + threadIdx.x;
  if (t < WORDS_PER_STEP) {
    mask_word_body(mask, k0, k1, t);
  } else if (t < WORDS_PER_STEP + 8192u) {
    int i = (int)(t - WORDS_PER_STEP);       // w1: h = i>>6, k = i&63
    int h = i >> 6, k = i & 63;
    float v = (k < 48) ? w1[h * 48 + k] : 0.f;
    short hi = bf16_rne(v);
    w1h[i] = hi;
    w1l[i] = bf16_rne(v - bf16_to_f(hi));
  } else if (t < WORDS_PER_STEP + 8192u + 2048u) {
    int j = (int)(t - WORDS_PER_STEP - 8192u);  // w2[o*128+k] direct
    float v = w2[j];
    short hi = bf16_rne(v);
    w2h[j] = hi;
    w2l[j] = bf16_rne(v - bf16_to_f(hi));
  }
}

// Step kernel A — MFMA version. 512 threads = 8 waves, 64 pixels/block.
// Phase 1: r12 perceive (fp32, plds) + bf16 hi/lo P into swizzled LDS.
// Phase 2: MLP1 as MFMA GEMM C1[pix][hid]: wave w = hid-tile w; 3-term split.
// Phase 3: +b1, relu, split H into swizzled LDS.
// Phase 4: MLP2 C2[pix][o]: wave pairs split K; partials -> red (aliased pBh).
// Phase 5: r12 epilogue verbatim (coalesced stores, mask, mid3c, pre).
__global__ __launch_bounds__(512) void step_a_kernel(
    const float* __restrict__ s,
    const short* __restrict__ w1h, const short* __restrict__ w1l,
    const short* __restrict__ w2h, const short* __restrict__ w2l,
    const float* __restrict__ bias1, const float* __restrict__ bias2,
    const unsigned* __restrict__ mask,
    float* __restrict__ mid, float* __restrict__ mid3c,
    unsigned char* __restrict__ pre) {
  __shared__ float plds[48][NPIXB];                 // 12.3 KB fp32 (identity)
  __shared__ __align__(16) short pBh[64 * 64];      // 8 KB  P hi (swizzled)
  __shared__ __align__(16) short pBl[64 * 64];      // 8 KB  P lo
  __shared__ __align__(16) short Hh[64 * 128];      // 16 KB H hi
  __shared__ __align__(16) short Hl[64 * 128];      // 16 KB H lo

  const int tid = threadIdx.x;
  const int lane = tid & 63;
  const int pix = lane;                              // perceive mapping
  const int w = __builtin_amdgcn_readfirstlane(tid >> 6);  // wave id 0..7
  const int pid0 = blockIdx.x * NPIXB;
  const int b = pid0 >> 14;
  const int r0 = pid0 & 16383;
  const int y = r0 >> 7, x0 = r0 & 127;
  const int x = x0 + pix;
  const int pid = pid0 + pix;

  // ---- phase 1: perceive (r12 body) + pB hi/lo packed writes ----
  const float* sb = s + b * IMG;
  const int ctr = y * WD + x;
  const bool yu = (y > 0), yd = (y < HT - 1), xl = (x > 0), xr = (x < WD - 1);
  float premax = -1e30f;
  float vid[2], vsx[2], vsy[2];
  #pragma unroll
  for (int cc = 0; cc < 2; ++cc) {
    const int c = 2 * w + cc;
    const float* sc = sb + c * PLANE + ctr;
    float a11 = sc[0];
    float a00 = (yu && xl) ? sc[-WD - 1] : 0.f;
    float a01 = yu         ? sc[-WD]     : 0.f;
    float a02 = (yu && xr) ? sc[-WD + 1] : 0.f;
    float a10 = xl         ? sc[-1]      : 0.f;
    float a12 = xr         ? sc[1]       : 0.f;
    float a20 = (yd && xl) ? sc[WD - 1]  : 0.f;
    float a21 = yd         ? sc[WD]      : 0.f;
    float a22 = (yd && xr) ? sc[WD + 1]  : 0.f;
    vid[cc] = a11;
    vsx[cc] = (a02 - a00) + 2.f * (a12 - a10) + (a22 - a20);
    vsy[cc] = (a20 - a00) + 2.f * (a21 - a01) + (a22 - a02);
    plds[c][pix]      = vid[cc];
    plds[16 + c][pix] = vsx[cc];
    plds[32 + c][pix] = vsy[cc];
    if (w == 1 && cc == 1) {             // c == 3, alive channel
      float m0 = fmaxf(fmaxf(a00, a01), fmaxf(a02, a10));
      float m1 = fmaxf(fmaxf(a11, a12), fmaxf(a20, a21));
      premax = fmaxf(fmaxf(m0, m1), a22);
    }
  }
  // pB element (pix,k): f16off = pix*64 + ((k>>3)^(pix&7))*8 + (k&7).
  // This thread owns k-pairs (2w,2w+1) in groups {0,16,32}.
  {
    unsigned* ph = (unsigned*)pBh;
    unsigned* pl = (unsigned*)pBl;
    #pragma unroll
    for (int g3 = 0; g3 < 3; ++g3) {
      float v0 = (g3 == 0) ? vid[0] : (g3 == 1) ? vsx[0] : vsy[0];
      float v1 = (g3 == 0) ? vid[1] : (g3 == 1) ? vsx[1] : vsy[1];
      int gk = g3 * 2 + (w >> 2);
      int sg = gk ^ (pix & 7);
      int idx = pix * 32 + sg * 4 + (w & 3);   // dword index
      short h0 = bf16_rne(v0), h1 = bf16_rne(v1);
      short l0 = bf16_rne(v0 - bf16_to_f(h0));
      short l1 = bf16_rne(v1 - bf16_to_f(h1));
      ph[idx] = (unsigned)(unsigned short)h0 | ((unsigned)(unsigned short)h1 << 16);
      pl[idx] = (unsigned)(unsigned short)l0 | ((unsigned)(unsigned short)l1 << 16);
    }
  }
  // zero pad granules gk=6,7 (k 48..63) — MFMA A must be finite
  if (tid < 256) {
    int zp = tid & 63, gk = 6 + ((tid >> 6) & 1);
    int sg = gk ^ (zp & 7);
    short* dst = ((tid >> 7) & 1) ? pBl : pBh;
    *(short8*)&dst[zp * 64 + sg * 8] = (short8){0,0,0,0,0,0,0,0};
  }
  __syncthreads();

  // ---- phase 2: MLP1 MFMAs. wave w = hid-tile w; B frags wave-constant ----
  const int hidb = 16 * w + (lane & 15);
  const int quad = lane >> 4;
  const short8 bh0 = *(const short8*)&w1h[hidb * 64 + quad * 8];
  const short8 bh1 = *(const short8*)&w1h[hidb * 64 + 32 + quad * 8];
  const short8 bl0 = *(const short8*)&w1l[hidb * 64 + quad * 8];
  const short8 bl1 = *(const short8*)&w1l[hidb * 64 + 32 + quad * 8];
  f32x4 acc[4];
  #pragma unroll
  for (int p = 0; p < 4; ++p) {
    acc[p] = (f32x4){0.f, 0.f, 0.f, 0.f};
    const int pixA = 16 * p + (lane & 15);
    const int s0 = (quad) ^ (pixA & 7);
    const int s1 = (4 + quad) ^ (pixA & 7);
    const short8 ah0 = *(const short8*)&pBh[pixA * 64 + s0 * 8];
    const short8 al0 = *(const short8*)&pBl[pixA * 64 + s0 * 8];
    const short8 ah1 = *(const short8*)&pBh[pixA * 64 + s1 * 8];
    const short8 al1 = *(const short8*)&pBl[pixA * 64 + s1 * 8];
    acc[p] = __builtin_amdgcn_mfma_f32_16x16x32_bf16(ah0, bh0, acc[p], 0, 0, 0);
    acc[p] = __builtin_amdgcn_mfma_f32_16x16x32_bf16(ah0, bl0, acc[p], 0, 0, 0);
    acc[p] = __builtin_amdgcn_mfma_f32_16x16x32_bf16(al0, bh0, acc[p], 0, 0, 0);
    acc[p] = __builtin_amdgcn_mfma_f32_16x16x32_bf16(ah1, bh1, acc[p], 0, 0, 0);
    acc[p] = __builtin_amdgcn_mfma_f32_16x16x32_bf16(ah1, bl1, acc[p], 0, 0, 0);
    acc[p] = __builtin_amdgcn_mfma_f32_16x16x32_bf16(al1, bh1, acc[p], 0, 0, 0);
  }

  // ---- phase 3: +b1, relu, split into H (C layout: col=lane&15,row=quad*4+reg) ----
  {
    const float b1v = bias1[hidb];
    const int gh = hidb >> 3;
    const int ho = hidb & 7;
    #pragma unroll
    for (int p = 0; p < 4; ++p) {
      #pragma unroll
      for (int reg = 0; reg < 4; ++reg) {
        float v = fmaxf(acc[p][reg] + b1v, 0.f);
        short hi = bf16_rne(v);
        short lo = bf16_rne(v - bf16_to_f(hi));
        int pixC = 16 * p + quad * 4 + reg;
        int sg = gh ^ (pixC & 15);
        Hh[pixC * 128 + sg * 8 + ho] = hi;
        Hl[pixC * 128 + sg * 8 + ho] = lo;
      }
    }
  }
  __syncthreads();

  // ---- phase 4: MLP2. wave pair (w&3, 4+(w&3)) splits K ----
  float* red = (float*)pBh;    // pB dead after phase 2; 64*17*4 B < 8 KB
  {
    const int p = w & 3;
    const int kk0 = (w >> 2) * 2;
    f32x4 acc2 = (f32x4){0.f, 0.f, 0.f, 0.f};
    #pragma unroll
    for (int kk = kk0; kk < kk0 + 2; ++kk) {
      const int pixA = 16 * p + (lane & 15);
      const int sg = (kk * 4 + quad) ^ (pixA & 15);
      const short8 a2h = *(const short8*)&Hh[pixA * 128 + sg * 8];
      const short8 a2l = *(const short8*)&Hl[pixA * 128 + sg * 8];
      const short8 c2h = *(const short8*)&w2h[(lane & 15) * 128 + kk * 32 + quad * 8];
      const short8 c2l = *(const short8*)&w2l[(lane & 15) * 128 + kk * 32 + quad * 8];
      acc2 = __builtin_amdgcn_mfma_f32_16x16x32_bf16(a2h, c2h, acc2, 0, 0, 0);
      acc2 = __builtin_amdgcn_mfma_f32_16x16x32_bf16(a2h, c2l, acc2, 0, 0, 0);
      acc2 = __builtin_amdgcn_mfma_f32_16x16x32_bf16(a2l, c2h, acc2, 0, 0, 0);
    }
    if (w >= 4) {
      #pragma unroll
      for (int reg = 0; reg < 4; ++reg)
        red[(16 * p + quad * 4 + reg) * 17 + (lane & 15)] = acc2[reg];
    }
    __syncthreads();
    if (w < 4) {
      #pragma unroll
      for (int reg = 0; reg < 4; ++reg)
        red[(16 * p + quad * 4 + reg) * 17 + (lane & 15)] += acc2[reg];
    }
    if (w == 1) pre[pid] = (premax > 0.1f) ? 1 : 0;
  }
  __syncthreads();

  // ---- phase 5: epilogue (r12 verbatim, red stride 17) ----
  #pragma unroll
  for (int k = 0; k < 2; ++k) {
    const int idx = tid + k * 512;
    const int p2 = idx & 63, o = idx >> 6;
    const int x2 = x0 + p2;
    float d = red[p2 * 17 + o] + bias2[o];
    d = fminf(fmaxf(d, -5.f), 5.f);
    unsigned mw = mask[((b * 16 + o) * HT + y) * 4 + (x2 >> 5)];
    float v = plds[o][p2] + (((mw >> (x2 & 31)) & 1u) ? d : 0.f);
    mid[b * IMG + o * PLANE + r0 + p2] = v;
    if (o == 3) mid3c[pid0 + p2] = v;
  }
}

// fmaskzero + next-step mask words (r15 structure).
__global__ __launch_bounds__(256) void fmaskzero_mask_kernel(
    const float* __restrict__ mid3c,
    const unsigned char* __restrict__ pre,
    float* __restrict__ mid,
    unsigned* __restrict__ mask_next, unsigned k0, unsigned k1) {
  int t = blockIdx.x * 256 + threadIdx.x;
  int b = t >> 14;
  int r = t & 16383;
  int y = r >> 7, x = r & 127;
  const float* m3 = mid3c + b * PLANE;
  float mx = -1e30f;
  #pragma unroll
  for (int dy = -1; dy <= 1; ++dy) {
    int yy = y + dy; if ((unsigned)yy >= HT) continue;
    #pragma unroll
    for (int dxx = -1; dxx <= 1; ++dxx) {
      int xx = x + dxx;
      if ((unsigned)xx < WD) mx = fmaxf(mx, m3[yy * WD + xx]);
    }
  }
  if (!((mx > 0.1f) && pre[t])) {
    float* mp = mid + b * IMG + r;
    #pragma unroll
    for (int c = 0; c < CH; ++c) mp[c * PLANE] = 0.f;
  }
  if (threadIdx.x < 128)
    mask_word_body(mask_next, k0, k1, blockIdx.x * 128u + threadIdx.x);
}

// Final step_b (r12 verbatim).
__global__ __launch_bounds__(256) void step_b_kernel(
    const float* __restrict__ mid,
    const unsigned char* __restrict__ pre,
    float* __restrict__ out) {
  int t = blockIdx.x * 256 + threadIdx.x;
  int cq = t >> 15;
  int qid = t & 32767;
  int b = qid >> 12;
  int r = qid & 4095;
  int y = r >> 5;
  int x0 = (r & 31) * 4;
  const float* m3 = mid + b * IMG + 3 * PLANE;

  float col[6];
  #pragma unroll
  for (int j = 0; j < 6; ++j) {
    int xx = x0 - 1 + j;
    float m = -1e30f;
    if ((unsigned)xx < WD) {
      #pragma unroll
      for (int dy = -1; dy <= 1; ++dy) {
        int yy = y + dy;
        if ((unsigned)yy < HT) m = fmaxf(m, m3[yy * WD + xx]);
      }
    }
    col[j] = m;
  }
  const unsigned char* pr = pre + b * PLANE + y * WD + x0;
  float f[4];
  #pragma unroll
  for (int i = 0; i < 4; ++i) {
    float mx = fmaxf(fmaxf(col[i], col[i + 1]), col[i + 2]);
    f[i] = ((mx > 0.1f) && pr[i]) ? 1.f : 0.f;
  }
  #pragma unroll
  for (int cc = 0; cc < 4; ++cc) {
    int c = cq * 4 + cc;
    const float4 v = *(const float4*)&mid[b * IMG + c * PLANE + y * WD + x0];
    float4 w;
    w.x = v.x * f[0]; w.y = v.y * f[1]; w.z = v.z * f[2]; w.w = v.w * f[3];
    *(float4*)&out[b * IMG + c * PLANE + y * WD + x0] = w;
  }
}

extern "C" void kernel_launch(void* const* d_in, const int* in_sizes, int n_in,
                              void* d_out, int out_size, void* d_ws, size_t ws_size,
                              hipStream_t stream) {
  const float* x  = (const float*)d_in[0];
  const float* w1 = (const float*)d_in[1];
  const float* b1 = (const float*)d_in[2];
  const float* w2 = (const float*)d_in[3];
  const float* b2 = (const float*)d_in[4];
  float* out = (float*)d_out;

  char* ws = (char*)d_ws;
  float* midbuf[2];
  midbuf[0] = (float*)ws;
  midbuf[1] = (float*)(ws + (size_t)NELEM * 4);
  float* mid3c = (float*)(ws + 2 * (size_t)NELEM * 4);
  unsigned char* pre = (unsigned char*)(ws + 2 * (size_t)NELEM * 4
                                           + (size_t)NPIX * 4);
  unsigned* mask = (unsigned*)(ws + 2 * (size_t)NELEM * 4
                                  + (size_t)NPIX * 4 + NPIX);
  char* wbase = ws + 2 * (size_t)NELEM * 4 + (size_t)NPIX * 4 + NPIX
                   + (size_t)NSTEPS * WORDS_PER_STEP * 4;
  short* w1h = (short*)wbase;                  // 8192 shorts
  short* w1l = w1h + 8192;
  short* w2h = w1l + 8192;                     // 2048 shorts
  short* w2l = w2h + 2048;

  // keys = jax.random.split(key(42), 8): keys[j] = threefry2x32((0,42),(0,j))
  unsigned keys[2 * NSTEPS];
  for (int j = 0; j < NSTEPS; ++j) {
    unsigned a, b;
    tf2x32(0u, 42u, 0u, (unsigned)j, a, b);
    keys[2 * j] = a; keys[2 * j + 1] = b;
  }

  wpack_mask0_kernel<<<(WORDS_PER_STEP + 8192 + 2048 + 255) / 256, 256, 0,
                       stream>>>(w1, w2, w1h, w1l, w2h, w2l,
                                 mask, keys[0], keys[1]);

  for (int s = 0; s < NSTEPS; ++s) {
    const float* src = (s == 0) ? x : midbuf[(s - 1) & 1];
    step_a_kernel<<<NGRP, 512, 0, stream>>>(
        src, w1h, w1l, w2h, w2l, b1, b2, mask + s * WORDS_PER_STEP,
        midbuf[s & 1], mid3c, pre);
    if (s < NSTEPS - 1)
      fmaskzero_mask_kernel<<<NPIX / 256, 256, 0, stream>>>(
          mid3c, pre, midbuf[s & 1],
          mask + (s + 1) * WORDS_PER_STEP, keys[2 * (s + 1)],
          keys[2 * (s + 1) + 1]);
  }
  step_b_kernel<<<NPIX / 256, 256, 0, stream>>>(
      midbuf[(NSTEPS - 1) & 1], pre, out);
}